// Round 2
// baseline (2103.453 us; speedup 1.0000x reference)
//
#include <hip/hip_runtime.h>
#include <hip/hip_bf16.h>

#define DIMC   128
#define HEADS  8
#define INNERD 1024
#define BATCH  8
#define XLEN   4096
#define NHEAD  64
#define EPSV   1e-5f
#define SCALEF 0.08838834764831845f   // 128^-0.5
#define XSPLIT 8
#define CHA    16

// ---------------------------------------------------------------------------
// prep kernels (~2 MB traffic total, negligible)
// ---------------------------------------------------------------------------
struct TP { const float* src; float* dst; int rows; int cols; };

__global__ void k_transpose4(TP t0, TP t1, TP t2, TP t3) {
  TP tp = (blockIdx.y == 0) ? t0 : (blockIdx.y == 1) ? t1 : (blockIdx.y == 2) ? t2 : t3;
  int idx = blockIdx.x * 256 + threadIdx.x;
  if (idx < tp.rows * tp.cols) {
    int r = idx / tp.cols, c = idx % tp.cols;
    tp.dst[c * tp.rows + r] = tp.src[idx];
  }
}

// gate folded: g_out[d] = sum_i Gt[i][d]*q_i + c0[d]
__global__ void k_gate_prep(const float* __restrict__ gt_pw, const float* __restrict__ gt_dw,
                            const float* __restrict__ gt_g, const float* __restrict__ gt_b,
                            const float* __restrict__ gt_m, const float* __restrict__ gt_v,
                            float* __restrict__ Gt, float* __restrict__ c0) {
  int d = threadIdx.x;                       // 128 threads, 1 block
  float s = 0.f;
  for (int i = 0; i < DIMC; ++i) {
    float a  = gt_g[i] * rsqrtf(gt_v[i] + EPSV);
    float w1 = gt_dw[i] * a;
    float w0 = gt_b[i] - gt_m[i] * a;
    float pw = gt_pw[d * DIMC + i];
    Gt[i * DIMC + d] = pw * w1;
    s += pw * w0;
  }
  c0[d] = s;
}

// fold BN into depthwise conv: dwf = dw*a, bfl = b - m*a  (p: 0=q,1=k,2=v)
__global__ void k_dw_prep(const float* dw0, const float* g0, const float* b0, const float* m0, const float* v0,
                          const float* dw1, const float* g1, const float* b1, const float* m1, const float* v1,
                          const float* dw2, const float* g2, const float* b2, const float* m2, const float* v2,
                          float* __restrict__ dwf, float* __restrict__ bfl) {
  int p = blockIdx.x, c = threadIdx.x;       // 3 blocks x 128 threads
  const float* dw = p == 0 ? dw0 : p == 1 ? dw1 : dw2;
  const float* g  = p == 0 ? g0  : p == 1 ? g1  : g2;
  const float* bb = p == 0 ? b0  : p == 1 ? b1  : b2;
  const float* m  = p == 0 ? m0  : p == 1 ? m1  : m2;
  const float* vv = p == 0 ? v0  : p == 1 ? v1  : v2;
  float a = g[c] * rsqrtf(vv[c] + EPSV);
  dwf[(p * DIMC + c) * 3 + 0] = dw[c * 3 + 0] * a;
  dwf[(p * DIMC + c) * 3 + 1] = dw[c * 3 + 1] * a;
  dwf[(p * DIMC + c) * 3 + 2] = dw[c * 3 + 2] * a;
  bfl[p * DIMC + c] = bb[c] - m[c] * a;
}

// ---------------------------------------------------------------------------
// Kernel A: kat[n,d,e] = SCALE * sum_x q[n,x,d] * softmax_e(k[n,x,:])
// q,k recomputed from x on the fly (dwconv+BN fold + per-head pw GEMM).
// grid (XSPLIT=8, NHEAD=64), 256 threads; fp32 atomicAdd into zeroed kat.
// ---------------------------------------------------------------------------
__global__ __launch_bounds__(256) void k_qk_kat(
    const float* __restrict__ x, const float* __restrict__ dwf,
    const float* __restrict__ bfl, const float* __restrict__ pwt,
    float* __restrict__ kat)
{
  __shared__ float xs[DIMC][CHA + 2];
  __shared__ float yq[DIMC][CHA];
  __shared__ float yk[DIMC][CHA];
  __shared__ float qt[CHA][DIMC];
  __shared__ float kt[CHA][DIMC];
  const int t = threadIdx.x;
  const int n = blockIdx.y;
  const int b = n >> 3, h = n & 7;
  const int xbase = blockIdx.x * (XLEN / XSPLIT);
  const int d0 = (t >> 4) * 8, e0 = (t & 15) * 8;   // outer-product coords
  const int gd = (t & 31) * 4, gx = (t >> 5) * 2;   // GEMM coords
  float acc[8][8];
  #pragma unroll
  for (int i = 0; i < 8; ++i)
    #pragma unroll
    for (int j = 0; j < 8; ++j) acc[i][j] = 0.f;

  for (int chunk = 0; chunk < (XLEN / XSPLIT) / CHA; ++chunk) {
    const int x0 = xbase + chunk * CHA;
    __syncthreads();                 // prev chunk's qt/kt reads done
    for (int idx = t; idx < DIMC * (CHA + 2); idx += 256) {
      int c = idx / (CHA + 2), j = idx % (CHA + 2);
      int xi = x0 + j - 1;
      xs[c][j] = (xi >= 0 && xi < XLEN) ? x[((size_t)b * DIMC + c) * XLEN + xi] : 0.f;
    }
    __syncthreads();
    // depthwise conv + folded BN for q (p=0) and k (p=1)
    for (int idx = t; idx < DIMC * CHA * 2; idx += 256) {
      int ph = idx >= DIMC * CHA;
      int r  = idx - ph * DIMC * CHA;
      int c  = r >> 4, xl = r & 15;
      const float* dw = dwf + ((size_t)ph * DIMC + c) * 3;
      float val = xs[c][xl] * dw[0] + xs[c][xl + 1] * dw[1] + xs[c][xl + 2] * dw[2]
                + bfl[ph * DIMC + c];
      if (ph == 0) yq[c][xl] = val; else yk[c][xl] = val;
    }
    __syncthreads();
    // per-head pointwise GEMM: qt/kt[xl][d] = sum_c y[c][xl] * pwt[c][h*128+d]
    float aq[2][4], ak[2][4];
    #pragma unroll
    for (int r = 0; r < 2; ++r)
      #pragma unroll
      for (int j = 0; j < 4; ++j) { aq[r][j] = 0.f; ak[r][j] = 0.f; }
    const float* pq = pwt + (size_t)h * DIMC + gd;
    const float* pk = pwt + 131072 + (size_t)h * DIMC + gd;
    #pragma unroll 4
    for (int c = 0; c < DIMC; ++c) {
      float4 wq = *(const float4*)(pq + (size_t)c * INNERD);
      float4 wk = *(const float4*)(pk + (size_t)c * INNERD);
      float q0 = yq[c][gx], q1 = yq[c][gx + 1];
      float k0 = yk[c][gx], k1 = yk[c][gx + 1];
      float wqv[4] = {wq.x, wq.y, wq.z, wq.w};
      float wkv[4] = {wk.x, wk.y, wk.z, wk.w};
      #pragma unroll
      for (int j = 0; j < 4; ++j) {
        aq[0][j] += wqv[j] * q0;  aq[1][j] += wqv[j] * q1;
        ak[0][j] += wkv[j] * k0;  ak[1][j] += wkv[j] * k1;
      }
    }
    #pragma unroll
    for (int r = 0; r < 2; ++r)
      #pragma unroll
      for (int j = 0; j < 4; ++j) {
        qt[gx + r][gd + j] = aq[r][j];
        kt[gx + r][gd + j] = ak[r][j];
      }
    __syncthreads();
    // softmax of each kt row (16 rows x 128); 16 lanes per row, 8 elems/lane
    {
      int p = t >> 4, l = t & 15;
      float vv[8];
      #pragma unroll
      for (int j = 0; j < 8; ++j) vv[j] = kt[p][l + 16 * j];
      float mx = vv[0];
      #pragma unroll
      for (int j = 1; j < 8; ++j) mx = fmaxf(mx, vv[j]);
      #pragma unroll
      for (int off = 8; off >= 1; off >>= 1) mx = fmaxf(mx, __shfl_xor(mx, off, 16));
      float s = 0.f;
      #pragma unroll
      for (int j = 0; j < 8; ++j) { vv[j] = __expf(vv[j] - mx); s += vv[j]; }
      #pragma unroll
      for (int off = 8; off >= 1; off >>= 1) s += __shfl_xor(s, off, 16);
      float inv = 1.f / s;
      #pragma unroll
      for (int j = 0; j < 8; ++j) kt[p][l + 16 * j] = vv[j] * inv;
    }
    __syncthreads();
    // outer-product accumulate: acc[d,e] += sum_p qt[p][d] * kt[p][e]
    #pragma unroll
    for (int p = 0; p < CHA; ++p) {
      float4 qa = *(const float4*)&qt[p][d0];
      float4 qb = *(const float4*)&qt[p][d0 + 4];
      float4 sa = *(const float4*)&kt[p][e0];
      float4 sb = *(const float4*)&kt[p][e0 + 4];
      float qv[8] = {qa.x, qa.y, qa.z, qa.w, qb.x, qb.y, qb.z, qb.w};
      float sv[8] = {sa.x, sa.y, sa.z, sa.w, sb.x, sb.y, sb.z, sb.w};
      #pragma unroll
      for (int i = 0; i < 8; ++i)
        #pragma unroll
        for (int j = 0; j < 8; ++j) acc[i][j] += qv[i] * sv[j];
    }
  }
  float* kp = kat + ((size_t)n * DIMC + d0) * DIMC + e0;
  #pragma unroll
  for (int i = 0; i < 8; ++i)
    #pragma unroll
    for (int j = 0; j < 8; ++j) atomicAdd(kp + i * DIMC + j, acc[i][j] * SCALEF);
}

// ---------------------------------------------------------------------------
// Kernel B: recompute q,v per 16-pos tile; gate + v@kat + final projection.
// grid (X/16=256, B=8), 256 threads. Writes d_out directly.
// ---------------------------------------------------------------------------
__global__ __launch_bounds__(256) void k_out_f(
    const float* __restrict__ x, const float* __restrict__ dwf,
    const float* __restrict__ bfl, const float* __restrict__ pwt,
    const float* __restrict__ kat, const float* __restrict__ Gt,
    const float* __restrict__ c0, const float* __restrict__ Wt,
    const float* __restrict__ outb, float* __restrict__ outp)
{
  __shared__ float xs[DIMC][18];
  __shared__ float yq[DIMC][16];
  __shared__ float yv[DIMC][16];
  __shared__ float qt[16][DIMC];
  __shared__ float vt[16][DIMC];
  __shared__ float Pt[DIMC][20];   // [e][xl], stride 20 -> 16B-aligned rows
  const int t   = threadIdx.x;
  const int b   = blockIdx.y;
  const int x0  = blockIdx.x * 16;
  const int gd  = (t & 31) * 4;    // 4 consecutive d/e per thread
  const int gx  = (t >> 5) * 2;    // 2 positions per thread
  const int o   = t & 127;         // final-GEMM: output row per lane
  const int xg2 = (t >> 7) * 8;    // final-GEMM: 8 positions per thread
  float acc2[8];
  #pragma unroll
  for (int j = 0; j < 8; ++j) acc2[j] = 0.f;

  for (int idx = t; idx < DIMC * 18; idx += 256) {
    int c = idx / 18, j = idx % 18;
    int xi = x0 + j - 1;
    xs[c][j] = (xi >= 0 && xi < XLEN) ? x[((size_t)b * DIMC + c) * XLEN + xi] : 0.f;
  }
  __syncthreads();
  // depthwise conv + folded BN for q (p=0) and v (p=2)
  for (int idx = t; idx < DIMC * 16 * 2; idx += 256) {
    int ph = idx >= DIMC * 16;          // 0 -> q, 1 -> v
    int r  = idx - ph * DIMC * 16;
    int c  = r >> 4, xl = r & 15;
    int p  = ph ? 2 : 0;
    const float* dw = dwf + ((size_t)p * DIMC + c) * 3;
    float val = xs[c][xl] * dw[0] + xs[c][xl + 1] * dw[1] + xs[c][xl + 2] * dw[2]
              + bfl[p * DIMC + c];
    if (!ph) yq[c][xl] = val; else yv[c][xl] = val;
  }

  for (int h = 0; h < HEADS; ++h) {
    const int n = b * HEADS + h;
    __syncthreads();               // yq/yv ready (h=0); prev head's Pt reads done
    // per-head pw GEMM -> qt, vt
    float aq[2][4], av[2][4];
    #pragma unroll
    for (int r = 0; r < 2; ++r)
      #pragma unroll
      for (int j = 0; j < 4; ++j) { aq[r][j] = 0.f; av[r][j] = 0.f; }
    const float* pq = pwt + (size_t)h * DIMC + gd;
    const float* pv = pwt + 2 * 131072 + (size_t)h * DIMC + gd;
    #pragma unroll 4
    for (int c = 0; c < DIMC; ++c) {
      float4 wq = *(const float4*)(pq + (size_t)c * INNERD);
      float4 wv = *(const float4*)(pv + (size_t)c * INNERD);
      float q0 = yq[c][gx], q1 = yq[c][gx + 1];
      float v0 = yv[c][gx], v1 = yv[c][gx + 1];
      float wqv[4] = {wq.x, wq.y, wq.z, wq.w};
      float wvv[4] = {wv.x, wv.y, wv.z, wv.w};
      #pragma unroll
      for (int j = 0; j < 4; ++j) {
        aq[0][j] += wqv[j] * q0;  aq[1][j] += wqv[j] * q1;
        av[0][j] += wvv[j] * v0;  av[1][j] += wvv[j] * v1;
      }
    }
    #pragma unroll
    for (int r = 0; r < 2; ++r)
      #pragma unroll
      for (int j = 0; j < 4; ++j) {
        qt[gx + r][gd + j] = aq[r][j];
        vt[gx + r][gd + j] = av[r][j];
      }
    __syncthreads();
    // gate matvec + v@kat
    float akv[2][4], ago[2][4];
    #pragma unroll
    for (int r = 0; r < 2; ++r)
      #pragma unroll
      for (int j = 0; j < 4; ++j) { akv[r][j] = 0.f; ago[r][j] = 0.f; }
    const float* katn = kat + (size_t)n * DIMC * DIMC;
    #pragma unroll 4
    for (int i = 0; i < DIMC; ++i) {
      float4 g4 = *(const float4*)(Gt + i * DIMC + gd);
      float4 k4 = *(const float4*)(katn + i * DIMC + gd);
      float gv[4] = {g4.x, g4.y, g4.z, g4.w};
      float kv[4] = {k4.x, k4.y, k4.z, k4.w};
      float qa = qt[gx][i],  qb2 = qt[gx + 1][i];
      float va = vt[gx][i],  vb2 = vt[gx + 1][i];
      #pragma unroll
      for (int j = 0; j < 4; ++j) {
        ago[0][j] += gv[j] * qa;  ago[1][j] += gv[j] * qb2;
        akv[0][j] += kv[j] * va;  akv[1][j] += kv[j] * vb2;
      }
    }
    float4 cc = *(const float4*)(c0 + gd);
    float cv[4] = {cc.x, cc.y, cc.z, cc.w};
    #pragma unroll
    for (int r = 0; r < 2; ++r) {
      int xl = gx + r;
      #pragma unroll
      for (int j = 0; j < 4; ++j) {
        float go  = ago[r][j] + cv[j];
        float sig = 1.f / (1.f + __expf(-go));
        Pt[gd + j][xl] = akv[r][j] + sig * vt[xl][gd + j];
      }
    }
    __syncthreads();
    // final projection accumulate: acc2[x] += sum_e Wt[h*128+e][o] * Pt[e][x]
    const float* Wh = Wt + (size_t)h * DIMC * DIMC;
    #pragma unroll 4
    for (int e = 0; e < DIMC; ++e) {
      float w = Wh[e * DIMC + o];
      float4 pa = *(const float4*)&Pt[e][xg2];
      float4 pb = *(const float4*)&Pt[e][xg2 + 4];
      float pv4[8] = {pa.x, pa.y, pa.z, pa.w, pb.x, pb.y, pb.z, pb.w};
      #pragma unroll
      for (int j = 0; j < 8; ++j) acc2[j] += w * pv4[j];
    }
  }
  // stage through LDS (reuse Pt) for coalesced global writes
  __syncthreads();
  float* Ost = &Pt[0][0];          // 128*17*4 = 8704 B <= 10240 B
  #pragma unroll
  for (int j = 0; j < 8; ++j) Ost[o * 17 + xg2 + j] = acc2[j];
  __syncthreads();
  for (int idx = t; idx < DIMC * 16; idx += 256) {
    int oo = idx >> 4, xl = idx & 15;
    outp[((size_t)b * DIMC + oo) * XLEN + x0 + xl] = Ost[oo * 17 + xl] + outb[oo];
  }
}

// ---------------------------------------------------------------------------
extern "C" void kernel_launch(void* const* d_in, const int* in_sizes, int n_in,
                              void* d_out, int out_size, void* d_ws, size_t ws_size,
                              hipStream_t stream) {
  (void)in_sizes; (void)n_in; (void)out_size; (void)ws_size;
  const float* x = (const float*)d_in[0];
  // q: 1..6, k: 7..12, v: 13..18 (dw,g,b,m,v,pw), gt: 19..24, out_w:25, out_b:26

  // small workspace layout (~6.4 MB total):
  char* ws = (char*)d_ws;
  float* kat = (float*)(ws);                            // 4,194,304 B
  float* pwt = (float*)(ws + 4194304);                  // 1,572,864 B (q,k,v transposed)
  float* Wt  = (float*)(ws + 4194304 + 1572864);        //   524,288 B
  float* Gt  = (float*)(ws + 4194304 + 1572864 + 524288);             // 65,536 B
  float* c0  = (float*)(ws + 4194304 + 1572864 + 524288 + 65536);     //    512 B
  float* dwf = (float*)(ws + 4194304 + 1572864 + 524288 + 65536 + 512);      // 4,608 B
  float* bfl = (float*)(ws + 4194304 + 1572864 + 524288 + 65536 + 512 + 4608); // 1,536 B

  hipMemsetAsync(kat, 0, (size_t)NHEAD * DIMC * DIMC * 4, stream);

  TP t0{(const float*)d_in[6],  pwt,                1024, 128};
  TP t1{(const float*)d_in[12], pwt + 131072,       1024, 128};
  TP t2{(const float*)d_in[18], pwt + 2 * 131072,   1024, 128};
  TP t3{(const float*)d_in[25], Wt,                 128, 1024};
  k_transpose4<<<dim3(512, 4), 256, 0, stream>>>(t0, t1, t2, t3);

  k_gate_prep<<<1, 128, 0, stream>>>(
      (const float*)d_in[24], (const float*)d_in[19], (const float*)d_in[20],
      (const float*)d_in[21], (const float*)d_in[22], (const float*)d_in[23], Gt, c0);

  k_dw_prep<<<3, 128, 0, stream>>>(
      (const float*)d_in[1],  (const float*)d_in[2],  (const float*)d_in[3],
      (const float*)d_in[4],  (const float*)d_in[5],
      (const float*)d_in[7],  (const float*)d_in[8],  (const float*)d_in[9],
      (const float*)d_in[10], (const float*)d_in[11],
      (const float*)d_in[13], (const float*)d_in[14], (const float*)d_in[15],
      (const float*)d_in[16], (const float*)d_in[17], dwf, bfl);

  k_qk_kat<<<dim3(XSPLIT, NHEAD), 256, 0, stream>>>(x, dwf, bfl, pwt, kat);
  k_out_f<<<dim3(XLEN / 16, BATCH), 256, 0, stream>>>(x, dwf, bfl, pwt, kat, Gt, c0, Wt,
                                                      (const float*)d_in[26],
                                                      (float*)d_out);
}

// Round 3
// 1319.766 us; speedup vs baseline: 1.5938x; 1.5938x over previous
//
#include <hip/hip_runtime.h>
#include <hip/hip_bf16.h>

#define DIMC   128
#define HEADS  8
#define BATCH  8
#define XLEN   4096
#define NHEAD  64
#define EPSV   1e-5f
#define SCALEF 0.08838834764831845f   // 128^-0.5
#define XSPLIT_A 8
#define TX     64

typedef __attribute__((ext_vector_type(8))) short bf16x8;
typedef __attribute__((ext_vector_type(4))) float f32x4;
#define MFMA(a,b,c) __builtin_amdgcn_mfma_f32_16x16x32_bf16((a),(b),(c),0,0,0)

__device__ __forceinline__ short f2bf(float f) {
  union { float f; unsigned u; } v; v.f = f;
  return (short)((v.u + 0x7fffu + ((v.u >> 16) & 1u)) >> 16);
}
__device__ __forceinline__ float bf2f(short h) {
  union { unsigned u; float f; } v; v.u = ((unsigned)(unsigned short)h) << 16;
  return v.f;
}
__device__ __forceinline__ unsigned pk2(float a, float b) {
  return (unsigned)(unsigned short)f2bf(a) | ((unsigned)(unsigned short)f2bf(b) << 16);
}

// LDS fragment loads. Row-major bf16 tiles, XOR-swizzled: byte ^= (row&7)<<4.
// ldY: row stride 256 B ([64 rows][128 cols]); ldT: row stride 128 B ([128][64]).
__device__ __forceinline__ bf16x8 ldY(const short* Y, int row, int kcb) {
  return *(const bf16x8*)((const char*)Y + row*256 + (kcb ^ ((row&7)<<4)));
}
__device__ __forceinline__ bf16x8 ldT(const short* Y, int row, int kcb) {
  return *(const bf16x8*)((const char*)Y + row*128 + (kcb ^ ((row&7)<<4)));
}

// ---------------------------------------------------------------------------
// prep kernels
// ---------------------------------------------------------------------------
// fold BN into depthwise conv: dwf = dw*a, bfl = b - m*a  (p: 0=q,1=k,2=v)
__global__ void k_dw_prep(const float* dw0, const float* g0, const float* b0, const float* m0, const float* v0,
                          const float* dw1, const float* g1, const float* b1, const float* m1, const float* v1,
                          const float* dw2, const float* g2, const float* b2, const float* m2, const float* v2,
                          float* __restrict__ dwf, float* __restrict__ bfl) {
  int p = blockIdx.x, c = threadIdx.x;
  const float* dw = p == 0 ? dw0 : p == 1 ? dw1 : dw2;
  const float* g  = p == 0 ? g0  : p == 1 ? g1  : g2;
  const float* bb = p == 0 ? b0  : p == 1 ? b1  : b2;
  const float* m  = p == 0 ? m0  : p == 1 ? m1  : m2;
  const float* vv = p == 0 ? v0  : p == 1 ? v1  : v2;
  float a = g[c] * rsqrtf(vv[c] + EPSV);
  dwf[(p * DIMC + c) * 3 + 0] = dw[c * 3 + 0] * a;
  dwf[(p * DIMC + c) * 3 + 1] = dw[c * 3 + 1] * a;
  dwf[(p * DIMC + c) * 3 + 2] = dw[c * 3 + 2] * a;
  bfl[p * DIMC + c] = bb[c] - m[c] * a;
}

// gate fold: g_out[x][e] = sum_i q[x][i]*Gt[i][e] + c0[e]
__global__ void k_gate_prep(const float* __restrict__ gt_pw, const float* __restrict__ gt_dw,
                            const float* __restrict__ gt_g, const float* __restrict__ gt_b,
                            const float* __restrict__ gt_m, const float* __restrict__ gt_v,
                            float* __restrict__ Gt, float* __restrict__ c0) {
  int d = threadIdx.x;
  float s = 0.f;
  for (int i = 0; i < DIMC; ++i) {
    float a  = gt_g[i] * rsqrtf(gt_v[i] + EPSV);
    float w1 = gt_dw[i] * a;
    float w0 = gt_b[i] - gt_m[i] * a;
    float pw = gt_pw[d * DIMC + i];
    Gt[i * DIMC + d] = pw * w1;
    s += pw * w0;
  }
  c0[d] = s;
}

// Wg_h[c][e] = sum_d Wq_h[c][d]*Gt[d][e],  Wq_h[c][d] = q_pw[h*128+d][c]
__global__ void k_wg(const float* __restrict__ q_pw, const float* __restrict__ Gt,
                     float* __restrict__ WgF) {
  const int h = blockIdx.x, cb = blockIdx.y, t = threadIdx.x;
  const int c = cb * 16 + (t >> 4);
  const int e0 = (t & 15) * 8;
  float acc[8] = {0.f,0.f,0.f,0.f,0.f,0.f,0.f,0.f};
  for (int d = 0; d < DIMC; ++d) {
    float wq = q_pw[((size_t)(h * DIMC + d)) * DIMC + c];
    const float* gr = Gt + d * DIMC + e0;
    #pragma unroll
    for (int j = 0; j < 8; ++j) acc[j] += wq * gr[j];
  }
  float* out = WgF + ((size_t)h * DIMC + c) * DIMC + e0;
  #pragma unroll
  for (int j = 0; j < 8; ++j) out[j] = acc[j];
}

// pack B-frags (proj weights, hi/lo) and A-frags (out_w, hi/lo) in MFMA lane order
__global__ void k_pack(const float* __restrict__ q_pw, const float* __restrict__ k_pw,
                       const float* __restrict__ v_pw, const float* __restrict__ out_w,
                       short* __restrict__ Wpk, short* __restrict__ Opk) {
  const int blk = blockIdx.x, t = threadIdx.x;
  if (blk < 48) {             // proj B-frag: value = pw[h*128 + nt*16 + (l&15)][kt*32 + (l>>4)*8 + j]
    const int p = blk / 16, h = (blk / 2) & 7, hl = blk & 1;
    const float* pw = p == 0 ? q_pw : p == 1 ? k_pw : v_pw;
    short* dst = Wpk + (size_t)((p * 8 + h) * 2 + hl) * 16384;
    for (int s = t; s < 2048; s += 256) {
      const int l = s & 63, kt = (s >> 6) >> 3, nt = (s >> 6) & 7;
      const int o = h * DIMC + nt * 16 + (l & 15);
      const int cb = kt * 32 + (l >> 4) * 8;
      #pragma unroll
      for (int j = 0; j < 8; ++j) {
        float wv = pw[(size_t)o * DIMC + cb + j];
        short hi = f2bf(wv);
        dst[s * 8 + j] = (hl == 0) ? hi : f2bf(wv - bf2f(hi));
      }
    }
  } else {                    // out_w A-frag: value = out_w[mt*16 + (l&15)][h*128 + kt*32 + (l>>4)*8 + j]
    const int m = blk - 48, h = m >> 1, hl = m & 1;
    short* dst = Opk + (size_t)(h * 2 + hl) * 16384;
    for (int s = t; s < 2048; s += 256) {
      const int l = s & 63, mt = (s >> 6) >> 2, kt = (s >> 6) & 3;
      const int o = mt * 16 + (l & 15);
      const int ib = h * DIMC + kt * 32 + (l >> 4) * 8;
      #pragma unroll
      for (int j = 0; j < 8; ++j) {
        float wv = out_w[(size_t)o * (DIMC * HEADS) + ib + j];
        short hi = f2bf(wv);
        dst[s * 8 + j] = (hl == 0) ? hi : f2bf(wv - bf2f(hi));
      }
    }
  }
}

__global__ void k_gpack(const float* __restrict__ WgF, short* __restrict__ Gpk) {
  const int h = blockIdx.x, t = threadIdx.x;
  const float* src = WgF + (size_t)h * 16384;
  short* dst = Gpk + (size_t)h * 16384;
  for (int s = t; s < 2048; s += 256) {
    const int l = s & 63, kt = (s >> 6) >> 3, nt = (s >> 6) & 7;
    const int cb = kt * 32 + (l >> 4) * 8, e = nt * 16 + (l & 15);
    #pragma unroll
    for (int j = 0; j < 8; ++j) dst[s * 8 + j] = f2bf(src[(size_t)(cb + j) * DIMC + e]);
  }
}

__global__ void k_katpk(const float* __restrict__ kat, short* __restrict__ katpk) {
  const int n = blockIdx.x, t = threadIdx.x;
  const float* kn = kat + (size_t)n * 16384;
  short* dst = katpk + (size_t)n * 16384;
  for (int s = t; s < 2048; s += 256) {
    const int l = s & 63, kt = (s >> 6) >> 3, nt = (s >> 6) & 7;
    const int db = kt * 32 + (l >> 4) * 8, e = nt * 16 + (l & 15);
    #pragma unroll
    for (int j = 0; j < 8; ++j) dst[s * 8 + j] = f2bf(kn[(size_t)(db + j) * DIMC + e]);
  }
}

// ---------------------------------------------------------------------------
// stage Y tiles: dwconv+BN for two projections -> swizzled bf16 LDS [64 x][128 c]
// ---------------------------------------------------------------------------
__device__ __forceinline__ void stage2(const float* __restrict__ x,
    const float* __restrict__ dwf, const float* __restrict__ bfl,
    int b, int xg0, int t, short* Y0, short* Y1, int p0, int p1)
{
  const int xl = t & 63, cg = t >> 6;
  const int xg = xg0 + xl;
  #pragma unroll
  for (int i = 0; i < 16; ++i) {
    const int c = 2 * (cg + 4 * i);
    float v0[2], v1[2];
    #pragma unroll
    for (int u = 0; u < 2; ++u) {
      const int cc = c + u;
      const float* xr = x + ((size_t)b * DIMC + cc) * XLEN + xg;
      float xm = (xg > 0) ? xr[-1] : 0.f;
      float xc = xr[0];
      float xp = (xg < XLEN - 1) ? xr[1] : 0.f;
      const float* d0 = dwf + (p0 * DIMC + cc) * 3;
      const float* d1 = dwf + (p1 * DIMC + cc) * 3;
      v0[u] = xm * d0[0] + xc * d0[1] + xp * d0[2] + bfl[p0 * DIMC + cc];
      v1[u] = xm * d1[0] + xc * d1[1] + xp * d1[2] + bfl[p1 * DIMC + cc];
    }
    const unsigned off = xl * 256 + ((c * 2) ^ ((xl & 7) << 4));
    *(unsigned*)((char*)Y0 + off) = pk2(v0[0], v0[1]);
    *(unsigned*)((char*)Y1 + off) = pk2(v1[0], v1[1]);
  }
}

// ---------------------------------------------------------------------------
// Kernel A: kat[n,d,e] = SCALE * sum_x q[n,x,d] * softmax_e(k[n,x,:])
// grid (8 x-splits, 64 n), 256 thr (4 waves). MFMA throughout.
// ---------------------------------------------------------------------------
__global__ __launch_bounds__(256) void k_kat2(
    const float* __restrict__ x, const float* __restrict__ dwf,
    const float* __restrict__ bfl, const short* __restrict__ Wpk,
    float* __restrict__ kat)
{
  __shared__ __align__(16) short Yq[TX * 128], Yk[TX * 128];
  __shared__ __align__(16) short QT[128 * TX], ST[128 * TX];
  const int t = threadIdx.x, w = t >> 6, l = t & 63;
  const int l15 = l & 15, lq = l >> 4;
  const int n = blockIdx.y, b = n >> 3, h = n & 7;
  const int xbase = blockIdx.x * (XLEN / XSPLIT_A);

  const short* WqHi = Wpk + (size_t)((0 * 8 + h) * 2 + 0) * 16384;
  const short* WqLo = Wpk + (size_t)((0 * 8 + h) * 2 + 1) * 16384;
  const short* WkHi = Wpk + (size_t)((1 * 8 + h) * 2 + 0) * 16384;
  const short* WkLo = Wpk + (size_t)((1 * 8 + h) * 2 + 1) * 16384;

  f32x4 ka[2][8];
  #pragma unroll
  for (int i = 0; i < 2; ++i)
    #pragma unroll
    for (int j = 0; j < 8; ++j) ka[i][j] = {0.f, 0.f, 0.f, 0.f};

  for (int ch = 0; ch < (XLEN / XSPLIT_A) / TX; ++ch) {
    __syncthreads();
    stage2(x, dwf, bfl, b, xbase + ch * TX, t, Yq, Yk, 0, 1);
    __syncthreads();

    // Q GEMM (weights hi+lo)
    f32x4 qa[8];
    #pragma unroll
    for (int j = 0; j < 8; ++j) qa[j] = {0.f, 0.f, 0.f, 0.f};
    #pragma unroll
    for (int kt = 0; kt < 4; ++kt) {
      bf16x8 a = ldY(Yq, w * 16 + l15, kt * 64 + lq * 16);
      #pragma unroll
      for (int nt = 0; nt < 8; ++nt) {
        bf16x8 bh = *(const bf16x8*)&WqHi[(kt * 8 + nt) * 512 + l * 8];
        bf16x8 bl = *(const bf16x8*)&WqLo[(kt * 8 + nt) * 512 + l * 8];
        qa[nt] = MFMA(a, bh, qa[nt]);
        qa[nt] = MFMA(a, bl, qa[nt]);
      }
    }
    // write Q^T[d][x]
    #pragma unroll
    for (int nt = 0; nt < 8; ++nt) {
      const int d = nt * 16 + l15;
      #pragma unroll
      for (int rp = 0; rp < 2; ++rp) {
        const int x2 = w * 16 + lq * 4 + rp * 2;
        *(unsigned*)((char*)QT + d * 128 + ((x2 * 2) ^ ((d & 7) << 4))) =
            pk2(qa[nt][rp * 2], qa[nt][rp * 2 + 1]);
      }
    }

    // K GEMM (weights hi+lo), reuse qa
    #pragma unroll
    for (int j = 0; j < 8; ++j) qa[j] = {0.f, 0.f, 0.f, 0.f};
    #pragma unroll
    for (int kt = 0; kt < 4; ++kt) {
      bf16x8 a = ldY(Yk, w * 16 + l15, kt * 64 + lq * 16);
      #pragma unroll
      for (int nt = 0; nt < 8; ++nt) {
        bf16x8 bh = *(const bf16x8*)&WkHi[(kt * 8 + nt) * 512 + l * 8];
        bf16x8 bl = *(const bf16x8*)&WkLo[(kt * 8 + nt) * 512 + l * 8];
        qa[nt] = MFMA(a, bh, qa[nt]);
        qa[nt] = MFMA(a, bl, qa[nt]);
      }
    }
    // in-register row softmax (row = x, spread over l15 lanes x 8 tiles)
    float inv[4];
    #pragma unroll
    for (int r = 0; r < 4; ++r) {
      float m = qa[0][r];
      #pragma unroll
      for (int nt = 1; nt < 8; ++nt) m = fmaxf(m, qa[nt][r]);
      m = fmaxf(m, __shfl_xor(m, 1)); m = fmaxf(m, __shfl_xor(m, 2));
      m = fmaxf(m, __shfl_xor(m, 4)); m = fmaxf(m, __shfl_xor(m, 8));
      float s = 0.f;
      #pragma unroll
      for (int nt = 0; nt < 8; ++nt) { float e = __expf(qa[nt][r] - m); qa[nt][r] = e; s += e; }
      s += __shfl_xor(s, 1); s += __shfl_xor(s, 2); s += __shfl_xor(s, 4); s += __shfl_xor(s, 8);
      inv[r] = 1.f / s;
    }
    // write S^T[e][x]
    #pragma unroll
    for (int nt = 0; nt < 8; ++nt) {
      const int e = nt * 16 + l15;
      #pragma unroll
      for (int rp = 0; rp < 2; ++rp) {
        const int x2 = w * 16 + lq * 4 + rp * 2;
        *(unsigned*)((char*)ST + e * 128 + ((x2 * 2) ^ ((e & 7) << 4))) =
            pk2(qa[nt][rp * 2] * inv[rp * 2], qa[nt][rp * 2 + 1] * inv[rp * 2 + 1]);
      }
    }
    __syncthreads();

    // kat accumulate: ka[mt][nt] += QT_A(d,x) x ST_B(x,e), K = 64
    #pragma unroll
    for (int kt2 = 0; kt2 < 2; ++kt2) {
      bf16x8 a0 = ldT(QT, w * 32 + l15,      kt2 * 64 + lq * 16);
      bf16x8 a1 = ldT(QT, w * 32 + 16 + l15, kt2 * 64 + lq * 16);
      #pragma unroll
      for (int nt = 0; nt < 8; ++nt) {
        bf16x8 bs = ldT(ST, nt * 16 + l15, kt2 * 64 + lq * 16);
        ka[0][nt] = MFMA(a0, bs, ka[0][nt]);
        ka[1][nt] = MFMA(a1, bs, ka[1][nt]);
      }
    }
  }
  #pragma unroll
  for (int mt = 0; mt < 2; ++mt)
    #pragma unroll
    for (int nt = 0; nt < 8; ++nt)
      #pragma unroll
      for (int r = 0; r < 4; ++r) {
        const int d = w * 32 + mt * 16 + lq * 4 + r;
        const int e = nt * 16 + l15;
        atomicAdd(&kat[((size_t)n * DIMC + d) * DIMC + e], ka[mt][nt][r] * SCALEF);
      }
}

// ---------------------------------------------------------------------------
// Kernel B: per 64-pos tile: recompute Yq,Yv; per head: V & gate GEMMs,
// v@kat, sigmoid-gate combine, final 1024->128 projection (accumulated).
// grid (64, 8), 256 thr.
// ---------------------------------------------------------------------------
__global__ __launch_bounds__(256) void k_out2(
    const float* __restrict__ x, const float* __restrict__ dwf,
    const float* __restrict__ bfl, const short* __restrict__ Wpk,
    const short* __restrict__ Gpk, const short* __restrict__ katpk,
    const short* __restrict__ Opk, const float* __restrict__ c0,
    const float* __restrict__ outb, float* __restrict__ outp)
{
  __shared__ __align__(16) short Yq[TX * 128], Yv[TX * 128];
  __shared__ __align__(16) short Vx[TX * 128], Tn[TX * 128];
  const int t = threadIdx.x, w = t >> 6, l = t & 63;
  const int l15 = l & 15, lq = l >> 4;
  const int b = blockIdx.y;
  const int x0 = blockIdx.x * TX;

  f32x4 oacc[2][4];
  #pragma unroll
  for (int i = 0; i < 2; ++i)
    #pragma unroll
    for (int j = 0; j < 4; ++j) oacc[i][j] = {0.f, 0.f, 0.f, 0.f};
  float c0v[8], obv[2][4];
  #pragma unroll
  for (int nt = 0; nt < 8; ++nt) c0v[nt] = c0[nt * 16 + l15];
  #pragma unroll
  for (int mt = 0; mt < 2; ++mt)
    #pragma unroll
    for (int r = 0; r < 4; ++r) obv[mt][r] = outb[w * 32 + mt * 16 + lq * 4 + r];

  stage2(x, dwf, bfl, b, x0, t, Yq, Yv, 0, 2);
  __syncthreads();

  for (int h = 0; h < HEADS; ++h) {
    const int n = b * HEADS + h;
    const short* WvHi = Wpk + (size_t)((2 * 8 + h) * 2 + 0) * 16384;
    const short* WvLo = Wpk + (size_t)((2 * 8 + h) * 2 + 1) * 16384;
    const short* Wg   = Gpk + (size_t)h * 16384;
    const short* Kp   = katpk + (size_t)n * 16384;

    // V GEMM (hi/lo) + gate GEMM (single)
    f32x4 va[8], ga[8];
    #pragma unroll
    for (int j = 0; j < 8; ++j) { va[j] = {0.f,0.f,0.f,0.f}; ga[j] = {0.f,0.f,0.f,0.f}; }
    #pragma unroll
    for (int kt = 0; kt < 4; ++kt) {
      bf16x8 aV = ldY(Yv, w * 16 + l15, kt * 64 + lq * 16);
      bf16x8 aQ = ldY(Yq, w * 16 + l15, kt * 64 + lq * 16);
      #pragma unroll
      for (int nt = 0; nt < 8; ++nt) {
        bf16x8 bh = *(const bf16x8*)&WvHi[(kt * 8 + nt) * 512 + l * 8];
        bf16x8 bl = *(const bf16x8*)&WvLo[(kt * 8 + nt) * 512 + l * 8];
        bf16x8 bg = *(const bf16x8*)&Wg[(kt * 8 + nt) * 512 + l * 8];
        va[nt] = MFMA(aV, bh, va[nt]);
        va[nt] = MFMA(aV, bl, va[nt]);
        ga[nt] = MFMA(aQ, bg, ga[nt]);
      }
    }
    // write V[x][d] (own wave strip -> no barrier needed)
    #pragma unroll
    for (int nt = 0; nt < 8; ++nt) {
      const int dd = nt * 16 + l15;
      #pragma unroll
      for (int r = 0; r < 4; ++r) {
        const int xr = w * 16 + lq * 4 + r;
        *(short*)((char*)Vx + xr * 256 + ((dd * 2) ^ ((xr & 7) << 4))) = f2bf(va[nt][r]);
      }
    }
    // KV GEMM: A = V[x][d] (own strip), B = kat frags
    f32x4 kv[8];
    #pragma unroll
    for (int j = 0; j < 8; ++j) kv[j] = {0.f, 0.f, 0.f, 0.f};
    #pragma unroll
    for (int kt = 0; kt < 4; ++kt) {
      bf16x8 aK = ldY(Vx, w * 16 + l15, kt * 64 + lq * 16);
      #pragma unroll
      for (int nt = 0; nt < 8; ++nt) {
        bf16x8 bk = *(const bf16x8*)&Kp[(kt * 8 + nt) * 512 + l * 8];
        kv[nt] = MFMA(aK, bk, kv[nt]);
      }
    }
    // combine: T = KV + sigmoid(GO + c0) * V  -> Tn[x][e]
    #pragma unroll
    for (int nt = 0; nt < 8; ++nt) {
      const int e = nt * 16 + l15;
      #pragma unroll
      for (int r = 0; r < 4; ++r) {
        const int xr = w * 16 + lq * 4 + r;
        float vv = bf2f(*(const short*)((const char*)Vx + xr * 256 + ((e * 2) ^ ((xr & 7) << 4))));
        float g = ga[nt][r] + c0v[nt];
        float sig = 1.f / (1.f + __expf(-g));
        *(short*)((char*)Tn + xr * 256 + ((e * 2) ^ ((xr & 7) << 4))) = f2bf(kv[nt][r] + sig * vv);
      }
    }
    __syncthreads();
    // final projection accumulate: oacc += out_w_h (hi/lo) x Tn
    const short* OHi = Opk + (size_t)(h * 2 + 0) * 16384;
    const short* OLo = Opk + (size_t)(h * 2 + 1) * 16384;
    #pragma unroll
    for (int kt = 0; kt < 4; ++kt) {
      bf16x8 a0h = *(const bf16x8*)&OHi[((w * 2 + 0) * 4 + kt) * 512 + l * 8];
      bf16x8 a1h = *(const bf16x8*)&OHi[((w * 2 + 1) * 4 + kt) * 512 + l * 8];
      bf16x8 a0l = *(const bf16x8*)&OLo[((w * 2 + 0) * 4 + kt) * 512 + l * 8];
      bf16x8 a1l = *(const bf16x8*)&OLo[((w * 2 + 1) * 4 + kt) * 512 + l * 8];
      #pragma unroll
      for (int nt4 = 0; nt4 < 4; ++nt4) {
        bf16x8 bt = ldY(Tn, nt4 * 16 + l15, kt * 64 + lq * 16);
        oacc[0][nt4] = MFMA(a0h, bt, oacc[0][nt4]);
        oacc[0][nt4] = MFMA(a0l, bt, oacc[0][nt4]);
        oacc[1][nt4] = MFMA(a1h, bt, oacc[1][nt4]);
        oacc[1][nt4] = MFMA(a1l, bt, oacc[1][nt4]);
      }
    }
    __syncthreads();
  }
  #pragma unroll
  for (int mt = 0; mt < 2; ++mt)
    #pragma unroll
    for (int nt4 = 0; nt4 < 4; ++nt4)
      #pragma unroll
      for (int r = 0; r < 4; ++r) {
        const int o = w * 32 + mt * 16 + lq * 4 + r;
        const int xx = x0 + nt4 * 16 + l15;
        outp[((size_t)b * DIMC + o) * XLEN + xx] = oacc[mt][nt4][r] + obv[mt][r];
      }
}

// ---------------------------------------------------------------------------
extern "C" void kernel_launch(void* const* d_in, const int* in_sizes, int n_in,
                              void* d_out, int out_size, void* d_ws, size_t ws_size,
                              hipStream_t stream) {
  (void)in_sizes; (void)n_in; (void)out_size; (void)ws_size;
  const float* x = (const float*)d_in[0];
  // q: 1..6, k: 7..12, v: 13..18 (dw,g,b,m,v,pw), gt: 19..24, out_w:25, out_b:26

  char* ws = (char*)d_ws;
  float* kat   = (float*)(ws);                       // 4 MB
  short* katpk = (short*)(ws + 4194304);             // 2 MB
  short* Wpk   = (short*)(ws + 6291456);             // 1.5 MB (q,k,v hi/lo B-frags)
  short* Opk   = (short*)(ws + 7864320);             // 512 KB (out_w hi/lo A-frags)
  short* Gpk   = (short*)(ws + 8388608);             // 256 KB (Wg B-frags)
  float* WgF   = (float*)(ws + 8650752);             // 512 KB
  float* Gt    = (float*)(ws + 9175040);             // 64 KB
  float* c0    = (float*)(ws + 9240576);             // 512 B
  float* dwf   = (float*)(ws + 9241088);             // 4.6 KB
  float* bfl   = (float*)(ws + 9245696);             // 1.5 KB

  hipMemsetAsync(kat, 0, (size_t)NHEAD * DIMC * DIMC * 4, stream);

  k_dw_prep<<<3, 128, 0, stream>>>(
      (const float*)d_in[1],  (const float*)d_in[2],  (const float*)d_in[3],
      (const float*)d_in[4],  (const float*)d_in[5],
      (const float*)d_in[7],  (const float*)d_in[8],  (const float*)d_in[9],
      (const float*)d_in[10], (const float*)d_in[11],
      (const float*)d_in[13], (const float*)d_in[14], (const float*)d_in[15],
      (const float*)d_in[16], (const float*)d_in[17], dwf, bfl);

  k_gate_prep<<<1, 128, 0, stream>>>(
      (const float*)d_in[24], (const float*)d_in[19], (const float*)d_in[20],
      (const float*)d_in[21], (const float*)d_in[22], (const float*)d_in[23], Gt, c0);

  k_wg<<<dim3(8, 8), 256, 0, stream>>>((const float*)d_in[6], Gt, WgF);

  k_pack<<<64, 256, 0, stream>>>((const float*)d_in[6], (const float*)d_in[12],
                                 (const float*)d_in[18], (const float*)d_in[25],
                                 Wpk, Opk);
  k_gpack<<<8, 256, 0, stream>>>(WgF, Gpk);

  k_kat2<<<dim3(XSPLIT_A, NHEAD), 256, 0, stream>>>(x, dwf, bfl, Wpk, kat);
  k_katpk<<<64, 256, 0, stream>>>(kat, katpk);
  k_out2<<<dim3(XLEN / TX, BATCH), 256, 0, stream>>>(x, dwf, bfl, Wpk, Gpk, katpk,
                                                     Opk, c0, (const float*)d_in[26],
                                                     (float*)d_out);
}